// Round 1
// 256.120 us; speedup vs baseline: 1.1910x; 1.1910x over previous
//
#include <hip/hip_runtime.h>

// Problem constants
#define NUM_EMB 1024
#define EMB_DIM 256
#define BATCH   32
#define HW      1024
#define Z_ELEMS (BATCH*EMB_DIM*HW)   // 8388608
#define LOSS_OFF Z_ELEMS
#define IDX_OFF (Z_ELEMS+1)

// ws: float[0] loss acc, uint[1] ticket, [16..1040) cnorm, [2048..34816) znorm
#define WS_CNORM_OFF 16
#define WS_ZNORM_OFF 2048

// out z-region scratch (all overwritten by k_gather at the very end):
//  halves [0 .. 524288)        : Bt — codebook*1024 as fp16, MFMA-B-frag tiled (512 KB)
//  ints   [262144 .. 294912)   : cand_cnt[32768]            (bytes 1.0-1.125 MB)
//  ints   [294912 .. 1343488)  : cand_idx[32768][32]        (bytes 1.125-5.125 MB)
//  floats [1343488 .. 2392064) : cand_val[32768][32]        (bytes 5.125-9.125 MB)
//  floats [2392064 .. 2424832) : s1z[32768] = sum_d|z_d|    (bytes 9.125-9.25 MB)
//  halves [6291456 .. 14680064): z16 — z as fp16, MFMA-A-frag tiled (bytes 12-28 MB)
#define CNT_IOFF  262144
#define CAND_IOFF 294912
#define FVAL_FOFF 1343488
#define S1Z_FOFF  2392064
#define Z16_HOFF  6291456
#define CAND_CAP  32

// Per-query filter threshold: T = T_SLOPE*S1z + T_BIAS.
// fp16 single-pass, codebook scaled x1024 (exact pow2): proven requirement
//   T >= 8u*cmax*S1z + ~1e-4   with u=2^-11, cmax=2^-10  =>  3.82e-6*S1z + 1e-4
// (covers fp16 input rounding both sides, MFMA fp32 accum, fp16 denorm flush,
//  and the fp32 fold/compare-space discrepancies vs the exact rescore recipe).
// Chosen slope/bias give 1.57x / 3x margin; typical T ~ 1.5e-3.
#define T_SLOPE 6.0e-6f
#define T_BIAS  3.0e-4f

typedef __attribute__((ext_vector_type(8))) _Float16 f16x8;
typedef __attribute__((ext_vector_type(4))) float f32x4;

// ---------------------------------------------------------------------------
// K0: fused prep, 292 blocks.
//  blk 0..3     cnorm[k] via exact pairwise tree (unchanged, feeds filter+rescore)
//  blk 4..131   znorm[n] exact tree + S1z[n] + z -> fp16 A-fragment tiles
//  blk 132..163 zero cand_cnt
//  blk 164..291 pack codebook*1024 -> fp16 Bt in MFMA B-fragment order
__global__ __launch_bounds__(256) void k_prep(const float* __restrict__ z,
                                              const float* __restrict__ cb,
                                              float* __restrict__ ws,
                                              float* __restrict__ out) {
    const int tid = threadIdx.x;
    const int blk = blockIdx.x;
    if (blk == 0 && tid == 0) { ws[0] = 0.0f; ((unsigned*)ws)[1] = 0u; }
    if (blk < 4) {
        int k = blk * 256 + tid;
        const float* row = cb + (size_t)k * EMB_DIM;
        float hsum[2];
#pragma unroll
        for (int h = 0; h < 2; ++h) {
            const float* a = row + h * 128;
            float r[8];
#pragma unroll
            for (int j = 0; j < 8; ++j) r[j] = __fmul_rn(a[j], a[j]);
            for (int i = 8; i < 128; i += 8)
#pragma unroll
                for (int j = 0; j < 8; ++j)
                    r[j] = __fadd_rn(r[j], __fmul_rn(a[i + j], a[i + j]));
            hsum[h] = __fadd_rn(__fadd_rn(__fadd_rn(r[0], r[1]), __fadd_rn(r[2], r[3])),
                                __fadd_rn(__fadd_rn(r[4], r[5]), __fadd_rn(r[6], r[7])));
        }
        ws[WS_CNORM_OFF + k] = __fadd_rn(hsum[0], hsum[1]);
    } else if (blk < 132) {
        int n = (blk - 4) * 256 + tid;
        int b = n >> 10, p = n & 1023;
        const float* base = z + (size_t)b * EMB_DIM * HW + p;
        _Float16* z16 = (_Float16*)out + Z16_HOFF;
        const int qb = n >> 6, r0 = n & 63;
        const int mt = r0 >> 4, l0 = r0 & 15;
        const size_t tb = (size_t)qb * 2048;      // f16x8 slots per query-block
        float hsum[2];
        float s1 = 0.0f;
#pragma unroll
        for (int h = 0; h < 2; ++h) {
            float racc[8], v[8];
#pragma unroll
            for (int j = 0; j < 8; ++j) v[j] = base[(size_t)(h * 128 + j) * HW];
            {
                int d0 = h * 128;
                int c = d0 >> 5, kh = (d0 >> 3) & 3;
                f16x8 g;
#pragma unroll
                for (int j = 0; j < 8; ++j) g[j] = (_Float16)v[j];
                *(f16x8*)(z16 + (tb + (size_t)(c * 4 + mt) * 64 + kh * 16 + l0) * 8) = g;
            }
#pragma unroll
            for (int j = 0; j < 8; ++j) { racc[j] = __fmul_rn(v[j], v[j]); s1 += fabsf(v[j]); }
            for (int i = 8; i < 128; i += 8) {
#pragma unroll
                for (int j = 0; j < 8; ++j) v[j] = base[(size_t)(h * 128 + i + j) * HW];
                int d0 = h * 128 + i;
                int c = d0 >> 5, kh = (d0 >> 3) & 3;
                f16x8 g;
#pragma unroll
                for (int j = 0; j < 8; ++j) g[j] = (_Float16)v[j];
                *(f16x8*)(z16 + (tb + (size_t)(c * 4 + mt) * 64 + kh * 16 + l0) * 8) = g;
#pragma unroll
                for (int j = 0; j < 8; ++j) {
                    racc[j] = __fadd_rn(racc[j], __fmul_rn(v[j], v[j]));
                    s1 += fabsf(v[j]);
                }
            }
            hsum[h] = __fadd_rn(__fadd_rn(__fadd_rn(racc[0], racc[1]), __fadd_rn(racc[2], racc[3])),
                                __fadd_rn(__fadd_rn(racc[4], racc[5]), __fadd_rn(racc[6], racc[7])));
        }
        ws[WS_ZNORM_OFF + n] = __fadd_rn(hsum[0], hsum[1]);
        out[S1Z_FOFF + n] = s1;
    } else if (blk < 164) {
        int i = (blk - 132) * 256 + tid;           // 0..8191, 4 ints each
        int4 zero = {0, 0, 0, 0};
        *(int4*)((int*)out + CNT_IOFF + (size_t)i * 4) = zero;
    } else {
        unsigned u = (unsigned)(blk - 164) * 256 + tid;   // 0..32767
        int lane = u & 63;
        int nt   = (u >> 6) & 15;
        int cc   = (u >> 10) & 7;
        int s    = (u >> 13) & 3;
        int code = s * 256 + nt * 16 + (lane & 15);
        int d0   = cc * 32 + (lane >> 4) * 8;
        const float* cr = cb + (size_t)code * EMB_DIM + d0;
        f16x8 v;
#pragma unroll
        for (int j = 0; j < 8; ++j) v[j] = (_Float16)(cr[j] * 1024.0f);
        _Float16* Bt = (_Float16*)out;
        *(f16x8*)(Bt + ((((size_t)(s * 8 + cc) * 16 + nt) * 64 + lane) * 8)) = v;
    }
}

// ---------------------------------------------------------------------------
// K1: MFMA candidate filter, single fp16 pass, no LDS staging.
// Block = 64 queries x one 256-code slab; every MFMA fragment (A from z16,
// B from Bt) is loaded per-lane directly from global — each (frag,lane) is
// consumed by exactly one thread, so LDS redistribution is pure overhead.
// s = c2 - 2*dot  (dot = acc/1024, folded as fmaf(-2^-9, acc, c2)).
// Slab-local min + per-query threshold T(S1z); appends (score,idx) pairs so
// k_rescore can prune to the GLOBAL min across slabs.
__global__ __launch_bounds__(256) void k_filter(const float* __restrict__ ws,
                                                float* __restrict__ out) {
    __shared__ float wm[4 * 64];
    __shared__ float thrq[64];

    const int tid = threadIdx.x;
    const int w = tid >> 6;            // wave 0..3
    const int l = tid & 63;
    const int s = blockIdx.y;          // code slab 0..3
    const int qb = blockIdx.x;
    const int nq0 = qb * 64;

    const f16x8* A8 = (const f16x8*)((const _Float16*)out + Z16_HOFF) + (size_t)qb * 2048;
    const f16x8* B8 = (const f16x8*)out + (size_t)s * 8192;

    f16x8 a[2][4], b[2][4];
#pragma unroll
    for (int mt = 0; mt < 4; ++mt) a[0][mt] = A8[mt * 64 + l];
#pragma unroll
    for (int nt = 0; nt < 4; ++nt) b[0][nt] = B8[(w * 4 + nt) * 64 + l];

    f32x4 acc[4][4];
#pragma unroll
    for (int mt = 0; mt < 4; ++mt)
#pragma unroll
        for (int nt = 0; nt < 4; ++nt) acc[mt][nt] = (f32x4)(0.0f);

#pragma unroll
    for (int c = 0; c < 8; ++c) {
        const int cur = c & 1, nxt = cur ^ 1;
        if (c < 7) {
#pragma unroll
            for (int mt = 0; mt < 4; ++mt) a[nxt][mt] = A8[(c + 1) * 256 + mt * 64 + l];
#pragma unroll
            for (int nt = 0; nt < 4; ++nt) b[nxt][nt] = B8[(c + 1) * 1024 + (w * 4 + nt) * 64 + l];
        }
#pragma unroll
        for (int mt = 0; mt < 4; ++mt)
#pragma unroll
            for (int nt = 0; nt < 4; ++nt)
                acc[mt][nt] = __builtin_amdgcn_mfma_f32_16x16x32_f16(a[cur][mt], b[cur][nt], acc[mt][nt], 0, 0, 0);
    }

    // epilogue: s = c2 - 2*dot, slab-local min, per-query threshold, append
    const float* cn = ws + WS_CNORM_OFF;
    float c2[4];
#pragma unroll
    for (int ntl = 0; ntl < 4; ++ntl)
        c2[ntl] = cn[s * 256 + (w * 4 + ntl) * 16 + (l & 15)];

    float vmin[4][4];
#pragma unroll
    for (int mt = 0; mt < 4; ++mt)
#pragma unroll
        for (int reg = 0; reg < 4; ++reg) vmin[mt][reg] = 3.4e38f;
#pragma unroll
    for (int mt = 0; mt < 4; ++mt)
#pragma unroll
        for (int ntl = 0; ntl < 4; ++ntl)
#pragma unroll
            for (int reg = 0; reg < 4; ++reg) {
                float sv = fmaf(-0.001953125f, acc[mt][ntl][reg], c2[ntl]);  // -2/1024
                acc[mt][ntl][reg] = sv;
                vmin[mt][reg] = fminf(vmin[mt][reg], sv);
            }
#pragma unroll
    for (int msk = 1; msk < 16; msk <<= 1)
#pragma unroll
        for (int mt = 0; mt < 4; ++mt)
#pragma unroll
            for (int reg = 0; reg < 4; ++reg)
                vmin[mt][reg] = fminf(vmin[mt][reg], __shfl_xor(vmin[mt][reg], msk, 64));
    if ((l & 15) == 0) {
#pragma unroll
        for (int mt = 0; mt < 4; ++mt)
#pragma unroll
            for (int reg = 0; reg < 4; ++reg)
                wm[w * 64 + mt * 16 + (l >> 4) * 4 + reg] = vmin[mt][reg];
    }
    __syncthreads();
    if (tid < 64) {
        float mq = fminf(fminf(wm[tid], wm[64 + tid]), fminf(wm[128 + tid], wm[192 + tid]));
        thrq[tid] = mq + fmaf(T_SLOPE, out[S1Z_FOFF + nq0 + tid], T_BIAS);
    }
    __syncthreads();

    int* cnt  = (int*)out + CNT_IOFF;
    int* cidx = (int*)out + CAND_IOFF;
    float* cval = out + FVAL_FOFF;
#pragma unroll
    for (int mt = 0; mt < 4; ++mt)
#pragma unroll
        for (int reg = 0; reg < 4; ++reg) {
            int m = mt * 16 + (l >> 4) * 4 + reg;
            float thr = thrq[m];
#pragma unroll
            for (int ntl = 0; ntl < 4; ++ntl) {
                if (acc[mt][ntl][reg] <= thr) {
                    int kg = s * 256 + (w * 4 + ntl) * 16 + (l & 15);
                    int nq = nq0 + m;
                    int slot = atomicAdd(&cnt[nq], 1);
                    if (slot < CAND_CAP) {
                        cidx[(size_t)nq * CAND_CAP + slot] = kg;
                        cval[(size_t)nq * CAND_CAP + slot] = acc[mt][ntl][reg];
                    }
                }
            }
        }
}

// ---------------------------------------------------------------------------
// K2: prune candidates to global filter-min + T; if a single survivor remains
// it IS the exact argmin (T covers 2x worst-case filter error + compare-space
// slack), else exact rescore via the bit-proven reference recipe —
// serial ascending-d fma dot, fold fl(fl(z2+c2) - fl(2*dot)), first-index ties.
__global__ __launch_bounds__(128) void k_rescore(const float* __restrict__ z,
                                                 const float* __restrict__ cb,
                                                 const float* __restrict__ ws,
                                                 float* __restrict__ out) {
    int n = blockIdx.x * 128 + threadIdx.x;
    int b = n >> 10, p = n & 1023;
    const float* zc = z + (size_t)b * EMB_DIM * HW + p;    // elem d: zc[d*HW]
    const int* cnt  = (const int*)out + CNT_IOFF;
    const int* cidx = (const int*)out + CAND_IOFF;
    const float* cval = out + FVAL_FOFF;
    const float* cn = ws + WS_CNORM_OFF;
    float z2 = ws[WS_ZNORM_OFF + n];
    int c = cnt[n];
    float best = 3.4e38f; int bestk = NUM_EMB;
    if (c <= CAND_CAP) {
        float tq = fmaf(T_SLOPE, out[S1Z_FOFF + n], T_BIAS);
        float minv = 3.4e38f;
        for (int i = 0; i < c; ++i) minv = fminf(minv, cval[(size_t)n * CAND_CAP + i]);
        float thr = minv + tq;
        int m = 0;
        int sk[CAND_CAP];
        for (int i = 0; i < c; ++i)
            if (cval[(size_t)n * CAND_CAP + i] <= thr) sk[m++] = cidx[(size_t)n * CAND_CAP + i];
        if (m == 1) {
            bestk = sk[0];
        } else {
            for (int i0 = 0; i0 < m; i0 += 4) {
                int nc = m - i0; if (nc > 4) nc = 4;
                int kk[4];
#pragma unroll
                for (int j = 0; j < 4; ++j) kk[j] = sk[i0 + (j < nc ? j : nc - 1)];
                float dot[4] = {0.0f, 0.0f, 0.0f, 0.0f};
                const float* r0 = cb + (size_t)kk[0] * EMB_DIM;
                const float* r1 = cb + (size_t)kk[1] * EMB_DIM;
                const float* r2 = cb + (size_t)kk[2] * EMB_DIM;
                const float* r3 = cb + (size_t)kk[3] * EMB_DIM;
#pragma unroll 4
                for (int d = 0; d < EMB_DIM; ++d) {
                    float zv = zc[(size_t)d * HW];
                    dot[0] = fmaf(zv, r0[d], dot[0]);
                    dot[1] = fmaf(zv, r1[d], dot[1]);
                    dot[2] = fmaf(zv, r2[d], dot[2]);
                    dot[3] = fmaf(zv, r3[d], dot[3]);
                }
                for (int j = 0; j < nc; ++j) {
                    float t1 = __fadd_rn(z2, cn[kk[j]]);
                    float sv = __fadd_rn(t1, __fmul_rn(-2.0f, dot[j]));
                    if (sv < best || (sv == best && kk[j] < bestk)) { best = sv; bestk = kk[j]; }
                }
            }
        }
    } else {           // overflow fallback (astronomically rare): exact full scan
        for (int k = 0; k < NUM_EMB; ++k) {
            const float* r = cb + (size_t)k * EMB_DIM;
            float dot = 0.0f;
            for (int d = 0; d < EMB_DIM; ++d) dot = fmaf(zc[(size_t)d * HW], r[d], dot);
            float t1 = __fadd_rn(z2, cn[k]);
            float sv = __fadd_rn(t1, __fmul_rn(-2.0f, dot));
            if (sv < best) { best = sv; bestk = k; }   // ascending k: strict < keeps first
        }
    }
    out[IDX_OFF + n] = (float)bestk;
}

// ---------------------------------------------------------------------------
// K3: gather z_q via LDS-staged codebook rows, straight-through write
// out = fl(z + fl(z_q - z)), loss partials + fused final scale via ticket.
// (Arithmetic order untouched — bit-exact vs previous passing version.)
__global__ __launch_bounds__(256) void k_gather(const float* __restrict__ z,
                                                const float* __restrict__ cb,
                                                float* __restrict__ out,
                                                float* __restrict__ ws) {
    __shared__ float s_cb[64][65];
    __shared__ int   s_idx[64];
    __shared__ float s_red[4];
    const int tid = threadIdx.x;
    const int b  = blockIdx.x >> 4;
    const int p0 = (blockIdx.x & 15) * 64;

    if (tid < 64)
        s_idx[tid] = (int)out[IDX_OFF + (size_t)b * HW + p0 + tid];
    __syncthreads();

    const int p    = tid & 63;
    const int cgrp = tid >> 6;
    const int row  = tid >> 2;
    const int q4   = tid & 3;
    const float* zrow = z   + (size_t)b * EMB_DIM * HW + p0 + p;
    float*       orow = out + (size_t)b * EMB_DIM * HW + p0 + p;

    float acc = 0.0f;
#pragma unroll 1
    for (int d0 = 0; d0 < EMB_DIM; d0 += 64) {
        const float* cr = cb + (size_t)s_idx[row] * EMB_DIM + d0;
#pragma unroll
        for (int pass = 0; pass < 4; ++pass) {
            int c = q4 * 4 + pass * 16;
            *(float4*)(&s_cb[row][c]) = *(const float4*)(cr + c);
        }
        __syncthreads();
#pragma unroll
        for (int j = 0; j < 16; ++j) {
            int c = cgrp * 16 + j;
            float zq = s_cb[p][c];
            float zv = zrow[(size_t)(d0 + c) * HW];
            float d  = zq - zv;
            orow[(size_t)(d0 + c) * HW] = zv + d;
            acc += d * d;
        }
        __syncthreads();
    }
#pragma unroll
    for (int off = 32; off > 0; off >>= 1) acc += __shfl_down(acc, off, 64);
    if ((tid & 63) == 0) s_red[tid >> 6] = acc;
    __syncthreads();
    if (tid == 0) {
        atomicAdd(ws, s_red[0] + s_red[1] + s_red[2] + s_red[3]);
        __threadfence();
        unsigned old = atomicAdd((unsigned int*)ws + 1, 1u);
        if (old == 511u) {
            float total = atomicAdd(ws, 0.0f);
            out[LOSS_OFF] = 1.25f * (total * (1.0f / 8388608.0f));
        }
    }
}

// ---------------------------------------------------------------------------
extern "C" void kernel_launch(void* const* d_in, const int* in_sizes, int n_in,
                              void* d_out, int out_size, void* d_ws, size_t ws_size,
                              hipStream_t stream) {
    const float* z  = (const float*)d_in[0];
    const float* cb = (const float*)d_in[1];
    float* out = (float*)d_out;
    float* ws  = (float*)d_ws;

    k_prep   <<<292, 256, 0, stream>>>(z, cb, ws, out);
    k_filter <<<dim3(512, 4), 256, 0, stream>>>(ws, out);
    k_rescore<<<256, 128, 0, stream>>>(z, cb, ws, out);
    k_gather <<<512, 256, 0, stream>>>(z, cb, out, ws);
}